// Round 3
// baseline (419.139 us; speedup 1.0000x reference)
//
#include <hip/hip_runtime.h>
#include <math.h>

typedef unsigned short u16;
typedef __bf16 bf16x8 __attribute__((ext_vector_type(8)));
typedef float f32x4 __attribute__((ext_vector_type(4)));

#define LSEQ 2048
#define NB   4
#define NE   1024
#define NHEAD 8
#define ND1  2048
#define NHD  256
#define NM   8192          // LSEQ*NB
#define CRP  4104          // pitch of shifted-coeff rows (elements, mult of 8)

__device__ __forceinline__ u16 f2bf(float f) {
  unsigned u = __float_as_uint(f);
  u += 0x7FFFu + ((u >> 16) & 1u);       // RTNE
  return (u16)(u >> 16);
}
__device__ __forceinline__ float bf2f(u16 h) {
  return __uint_as_float(((unsigned)h) << 16);
}

// ---------------- f32 -> bf16 bulk convert of the 3 weight matrices ----------
__global__ __launch_bounds__(256) void cvt3_kernel(const float* __restrict__ a,
                                                   const float* __restrict__ b,
                                                   const float* __restrict__ c,
                                                   u16* __restrict__ da,
                                                   u16* __restrict__ db,
                                                   u16* __restrict__ dc) {
  int i = blockIdx.x * 256 + threadIdx.x;      // < 3*524288
  const float* s; u16* d; int off;
  if (i < 524288)        { s = a; d = da; off = i; }
  else if (i < 1048576)  { s = b; d = db; off = i - 524288; }
  else                   { s = c; d = dc; off = i - 1048576; }
  float4 v = ((const float4*)s)[off];
  ushort4 o;
  o.x = f2bf(v.x); o.y = f2bf(v.y); o.z = f2bf(v.z); o.w = f2bf(v.w);
  ((ushort4*)d)[off] = o;
}

// ---------------- build 8 shifted copies of reversed toeplitz coeffs ----------
// cr[h][mm] = c_h[4094-mm] where c_h[t+2047]= (t==0? zero : t>0? pos[t-1] : neg[-t-1])
// cr8[(h*8+s)][m] = cr[h][m+s]  (0 beyond 4094), pitch CRP.
__global__ __launch_bounds__(256) void build_cr8(const float* __restrict__ pos,
                                                 const float* __restrict__ zero,
                                                 const float* __restrict__ neg,
                                                 u16* __restrict__ cr8) {
  int h = blockIdx.x >> 3, s = blockIdx.x & 7;
  u16* out = cr8 + (size_t)blockIdx.x * CRP;
  for (int m = threadIdx.x; m < CRP; m += 256) {
    int mm = m + s;
    float val = 0.f;
    if (mm <= 4094) {
      int t = 2047 - mm;                  // t = i - j
      if (t == 0)      val = zero[h];
      else if (t > 0)  val = pos[h * (LSEQ - 1) + t - 1];
      else             val = neg[h * (LSEQ - 1) + (-t) - 1];
    }
    out[m] = f2bf(val);
  }
}

// ---------------- RMSNorm: x = q / (||q||/sqrt(E) + 1e-8), bf16 out ----------
__global__ __launch_bounds__(256) void rmsnorm_kernel(const float* __restrict__ q,
                                                      u16* __restrict__ x) {
  int row = blockIdx.x;
  float4 v = ((const float4*)(q + (size_t)row * NE))[threadIdx.x];
  float ss = v.x * v.x + v.y * v.y + v.z * v.z + v.w * v.w;
  #pragma unroll
  for (int off = 32; off > 0; off >>= 1) ss += __shfl_down(ss, off, 64);
  __shared__ float wss[4];
  int wave = threadIdx.x >> 6, lane = threadIdx.x & 63;
  if (lane == 0) wss[wave] = ss;
  __syncthreads();
  float tot = wss[0] + wss[1] + wss[2] + wss[3];
  float scale = 1.f / (sqrtf(tot) * 0.03125f + 1e-8f);
  ushort4 o;
  o.x = f2bf(v.x * scale); o.y = f2bf(v.y * scale);
  o.z = f2bf(v.z * scale); o.w = f2bf(v.w * scale);
  ((ushort4*)(x + (size_t)row * NE))[threadIdx.x] = o;
}

// ---------------- transpose v (rows (j,b), cols (h,d)) -> vT[h][b*256+d][j] --
// 64(j) x 64(d) tile; ushort4 global loads+stores; LDS s[d][j] pad 72.
__global__ __launch_bounds__(256) void transpose_v(const u16* __restrict__ v,
                                                   u16* __restrict__ vT) {
  __shared__ u16 s[64][72];
  int j0 = blockIdx.x * 64, d0 = blockIdx.y * 64;
  int h = blockIdx.z >> 2, b = blockIdx.z & 3;
  #pragma unroll
  for (int it = 0; it < 4; ++it) {
    int slot = threadIdx.x + it * 256;         // 0..1023
    int r = slot >> 4, c4 = slot & 15;         // j row, d-quad
    ushort4 val = *(const ushort4*)&v[((size_t)(j0 + r) * NB + b) * ND1 + h * NHD + d0 + c4 * 4];
    s[c4 * 4 + 0][r] = val.x;
    s[c4 * 4 + 1][r] = val.y;
    s[c4 * 4 + 2][r] = val.z;
    s[c4 * 4 + 3][r] = val.w;
  }
  __syncthreads();
  #pragma unroll
  for (int it = 0; it < 4; ++it) {
    int slot = threadIdx.x + it * 256;
    int r = slot >> 4, c4 = slot & 15;         // d row, j-quad
    ushort4 val = *(const ushort4*)&s[r][c4 * 4];
    *(ushort4*)&vT[((size_t)h * (NB * NHD) + b * NHD + d0 + r) * LSEQ + j0 + c4 * 4] = val;
  }
}

// ---------------- generic 128x128 MFMA GEMM, C = A(MxK) * W(NxK)^T -----------
// Round-1 proven staging: uint4 register roundtrip into padded LDS (LDA=72).
// MODE 0: C(bf16) = silu(acc + bias[n]); blockIdx.z selects {u,v} weight/bias/dst
// MODE 1: A staged from cr8 (toeplitz), epilogue u *= acc   (head GEMM, z=u*y)
// MODE 2: Cf(f32) = acc + bias[n] + resid[m*N+n]            (output GEMM)
#define LDA 72
template <int MODE>
__global__ __launch_bounds__(256) void gemm_kernel(
    const u16* __restrict__ A, const u16* __restrict__ Bw,
    const float* __restrict__ bias, const float* __restrict__ bias2,
    const float* __restrict__ resid,
    u16* __restrict__ Cbf, float* __restrict__ Cf,
    int Msz, int Nsz, int Ksz) {
  __shared__ __align__(16) u16 As[128 * LDA];
  __shared__ __align__(16) u16 Ws[128 * LDA];

  const int tid = threadIdx.x;
  const int lane = tid & 63, wave = tid >> 6;
  const int wr = (wave >> 1) * 64, wc = (wave & 1) * 64;
  const int lr = lane & 15, lq = lane >> 4;
  const int i0 = blockIdx.y * 128, n0 = blockIdx.x * 128;

  const u16* Bh = Bw;
  const u16* Acr = A;
  const float* bp = bias;
  u16* Cb = Cbf;
  if (MODE == 1) {
    Bh  = Bw + (size_t)blockIdx.z * Nsz * Ksz;   // vT head base
    Acr = A + (size_t)blockIdx.z * 8 * CRP;      // cr8 head base
  }
  if (MODE == 0) {
    Bh = Bw + (size_t)blockIdx.z * Nsz * Ksz;    // u_w / v_w (contiguous)
    bp = blockIdx.z ? bias2 : bias;
    Cb = Cbf + (size_t)blockIdx.z * (size_t)Msz * Nsz;  // u / v (contiguous)
  }

  f32x4 acc[4][4];
  #pragma unroll
  for (int a = 0; a < 4; ++a)
    #pragma unroll
    for (int b = 0; b < 4; ++b) acc[a][b] = (f32x4){0.f, 0.f, 0.f, 0.f};

  const int nkt = Ksz >> 6;
  for (int kt = 0; kt < nkt; ++kt) {
    // ---- stage A tile (128 x 64) ----
    #pragma unroll
    for (int it = 0; it < 4; ++it) {
      int vv = tid + 256 * it;
      int r = vv >> 3, c8 = vv & 7;
      uint4 d;
      if (MODE != 1) {
        d = *(const uint4*)(A + (size_t)(i0 + r) * Ksz + kt * 64 + c8 * 8);
      } else {
        int p = 2047 - (i0 + r) + kt * 64;       // cr index of column 0
        int s = p & 7, qq = p - s;               // 8-aligned base in copy s
        d = *(const uint4*)(Acr + (size_t)s * CRP + qq + c8 * 8);
      }
      *(uint4*)&As[r * LDA + c8 * 8] = d;
    }
    // ---- stage W tile (128 x 64) ----
    #pragma unroll
    for (int it = 0; it < 4; ++it) {
      int vv = tid + 256 * it;
      int r = vv >> 3, c8 = vv & 7;
      uint4 d = *(const uint4*)(Bh + (size_t)(n0 + r) * Ksz + kt * 64 + c8 * 8);
      *(uint4*)&Ws[r * LDA + c8 * 8] = d;
    }
    __syncthreads();
    #pragma unroll
    for (int ks = 0; ks < 2; ++ks) {
      bf16x8 af[4], bfr[4];
      #pragma unroll
      for (int rt = 0; rt < 4; ++rt)
        af[rt] = *(const bf16x8*)&As[(wr + rt * 16 + lr) * LDA + ks * 32 + lq * 8];
      #pragma unroll
      for (int ct = 0; ct < 4; ++ct)
        bfr[ct] = *(const bf16x8*)&Ws[(wc + ct * 16 + lr) * LDA + ks * 32 + lq * 8];
      #pragma unroll
      for (int rt = 0; rt < 4; ++rt)
        #pragma unroll
        for (int ct = 0; ct < 4; ++ct)
          acc[rt][ct] = __builtin_amdgcn_mfma_f32_16x16x32_bf16(
              af[rt], bfr[ct], acc[rt][ct], 0, 0, 0);
    }
    __syncthreads();
  }

  // ---- epilogue ----
  #pragma unroll
  for (int rt = 0; rt < 4; ++rt) {
    #pragma unroll
    for (int ct = 0; ct < 4; ++ct) {
      int col = n0 + wc + ct * 16 + lr;
      #pragma unroll
      for (int reg = 0; reg < 4; ++reg) {
        int row = i0 + wr + rt * 16 + lq * 4 + reg;
        float yv = acc[rt][ct][reg];
        if (MODE == 0) {
          float t = yv + bp[col];
          t = t / (1.f + __expf(-t));            // silu
          Cb[(size_t)row * Nsz + col] = f2bf(t);
        } else if (MODE == 1) {
          int b = col >> 8, d = col & 255;       // col = b*256 + d
          size_t ui = ((size_t)row * NB + b) * ND1 + (size_t)blockIdx.z * NHD + d;
          float uv = bf2f(Cbf[ui]);
          Cbf[ui] = f2bf(uv * yv);               // z = u * y, in place
        } else {
          size_t oi = (size_t)row * Nsz + col;
          Cf[oi] = yv + bias[col] + resid[oi];
        }
      }
    }
  }
}

extern "C" void kernel_launch(void* const* d_in, const int* in_sizes, int n_in,
                              void* d_out, int out_size, void* d_ws, size_t ws_size,
                              hipStream_t stream) {
  const float* q    = (const float*)d_in[0];
  const float* uw   = (const float*)d_in[3];
  const float* ub   = (const float*)d_in[4];
  const float* vw   = (const float*)d_in[5];
  const float* vb   = (const float*)d_in[6];
  const float* ow   = (const float*)d_in[7];
  const float* ob   = (const float*)d_in[8];
  const float* pos  = (const float*)d_in[9];
  const float* zero = (const float*)d_in[10];
  const float* neg  = (const float*)d_in[11];
  float* out = (float*)d_out;

  char* ws = (char*)d_ws;
  u16* x   = (u16*)(ws + 0);            // 8192x1024 bf16 = 16 MiB
  u16* uwb = (u16*)(ws + 16777216);     // 4 MiB  (uwb,vwb contiguous!)
  u16* vwb = (u16*)(ws + 20971520);     // 4 MiB
  u16* owb = (u16*)(ws + 25165824);     // 4 MiB
  u16* u   = (u16*)(ws + 29360128);     // 8192x2048 bf16 = 32 MiB (later z); u,v contiguous!
  u16* v   = (u16*)(ws + 62914560);     // 32 MiB
  u16* vT  = (u16*)(ws + 96468992);     // 32 MiB
  u16* cr8 = (u16*)(ws + 130023424);    // 8*8*4104*2 = 513 KiB

  cvt3_kernel<<<6144, 256, 0, stream>>>(uw, vw, ow, uwb, vwb, owb);
  build_cr8<<<64, 256, 0, stream>>>(pos, zero, neg, cr8);
  rmsnorm_kernel<<<NM, 256, 0, stream>>>(q, x);

  // u = silu(x @ uw^T + ub), v = silu(x @ vw^T + vb) — fused via grid.z
  gemm_kernel<0><<<dim3(16, 64, 2), 256, 0, stream>>>(x, uwb, ub, vb, nullptr,
                                                      u, nullptr, NM, ND1, NE);
  // vT[h][b*256+d][j] = v[(j,b)][h*256+d]
  transpose_v<<<dim3(32, 4, 32), 256, 0, stream>>>(v, vT);
  // per head: y = T_h @ vT_h^T ; z = u*y in place (in u buffer)
  gemm_kernel<1><<<dim3(8, 16, 8), 256, 0, stream>>>(cr8, vT, nullptr, nullptr, nullptr,
                                                     u, nullptr, LSEQ, NB * NHD, LSEQ);
  // out = z @ ow^T + ob + q
  gemm_kernel<2><<<dim3(8, 64, 1), 256, 0, stream>>>(u, owb, ob, nullptr, q,
                                                     u, out, NM, NE, ND1);
}